// Round 6
// baseline (101.238 us; speedup 1.0000x reference)
//
#include <hip/hip_runtime.h>

// ---- fast-path compile-time geometry (gated on BN==65536) ----
#define NPB     128        // nodes per coarse bucket
#define NCOARSE 512        // 65536 / 128
#define SCAN_BS 1024       // elements per scan1 block

// pos[b,n,j] = sum_i rel[b,n,i] * basis[b,i,j]
__global__ void pos_kernel(const float* __restrict__ rel,
                           const float* __restrict__ basis,
                           float* __restrict__ pos,
                           int BN, int N) {
    int idx = blockIdx.x * blockDim.x + threadIdx.x;
    if (idx >= BN) return;
    int b = idx / N;
    const float* bm = basis + b * 9;
    float x = rel[idx * 3 + 0], y = rel[idx * 3 + 1], z = rel[idx * 3 + 2];
    pos[idx * 3 + 0] = x * bm[0] + y * bm[3] + z * bm[6];
    pos[idx * 3 + 1] = x * bm[1] + y * bm[4] + z * bm[7];
    pos[idx * 3 + 2] = x * bm[2] + y * bm[5] + z * bm[8];
}

// Phase A: per-block histogram over 512 coarse buckets -> ghist[bucket*NBLK + blk]
template <int NBLK>
__global__ void hist_kernel(const int* __restrict__ src,
                            const int* __restrict__ bch,
                            int* __restrict__ ghist,
                            int E, int N, int chunk) {
    __shared__ int h[NCOARSE];
    int tid = threadIdx.x, blk = blockIdx.x;
    for (int t = tid; t < NCOARSE; t += 256) h[t] = 0;
    __syncthreads();
    int lo = blk * chunk, hi = min(E, lo + chunk);
    for (int e0 = lo + tid * 4; e0 < hi; e0 += 1024) {
        if (e0 + 3 < hi) {
            int4 s4 = *(const int4*)(src + e0);
            int4 b4 = *(const int4*)(bch + e0);
            atomicAdd(&h[(b4.x * N + s4.x) >> 7], 1);
            atomicAdd(&h[(b4.y * N + s4.y) >> 7], 1);
            atomicAdd(&h[(b4.z * N + s4.z) >> 7], 1);
            atomicAdd(&h[(b4.w * N + s4.w) >> 7], 1);
        } else {
            for (int e = e0; e < hi; ++e)
                atomicAdd(&h[(bch[e] * N + src[e]) >> 7], 1);
        }
    }
    __syncthreads();
    for (int t = tid; t < NCOARSE; t += 256) ghist[t * NBLK + blk] = h[t];
}

// Phase B1: scan 1024-element tiles (exclusive, in place), emit tile sums
__global__ void scan1_kernel(int* __restrict__ g, int* __restrict__ bsums) {
    __shared__ int tp[256];
    int tid = threadIdx.x;
    int base = blockIdx.x * SCAN_BS + tid * 4;
    int v0 = g[base], v1 = g[base + 1], v2 = g[base + 2], v3 = g[base + 3];
    int s = v0 + v1 + v2 + v3;
    tp[tid] = s;
    for (int off = 1; off < 256; off <<= 1) {
        __syncthreads();
        int t = (tid >= off) ? tp[tid - off] : 0;
        __syncthreads();
        tp[tid] += t;
    }
    __syncthreads();
    int incl = tp[tid];
    int excl = incl - s;
    g[base]     = excl;
    g[base + 1] = excl + v0;
    g[base + 2] = excl + v0 + v1;
    g[base + 3] = excl + v0 + v1 + v2;
    if (tid == 255) bsums[blockIdx.x] = incl;
}

// Phase B2: exclusive scan of tile sums (n <= 1024), one block
__global__ void scan2_kernel(int* __restrict__ bsums, int n) {
    __shared__ int tp[1024];
    int tid = threadIdx.x;
    int v = (tid < n) ? bsums[tid] : 0;
    tp[tid] = v;
    for (int off = 1; off < 1024; off <<= 1) {
        __syncthreads();
        int t = (tid >= off) ? tp[tid - off] : 0;
        __syncthreads();
        tp[tid] += t;
    }
    __syncthreads();
    if (tid < n) bsums[tid] = tp[tid] - v;
}

// Phase C: recompute contribution, write record into its bucket region (LDS cursors)
template <int NBLK>
__global__ void scatter_kernel(const float* __restrict__ pos,
                               const float* __restrict__ shifts,
                               const int* __restrict__ src,
                               const int* __restrict__ dst,
                               const int* __restrict__ bch,
                               const int* __restrict__ ghist,
                               const int* __restrict__ bsums,
                               float4* __restrict__ sorted,
                               int E, int N, int chunk) {
    __shared__ int cur[NCOARSE];
    int tid = threadIdx.x, blk = blockIdx.x;
    for (int t = tid; t < NCOARSE; t += 256) {
        int idx = t * NBLK + blk;
        cur[t] = ghist[idx] + bsums[idx >> 10];
    }
    __syncthreads();
    int lo = blk * chunk, hi = min(E, lo + chunk);
    for (int e0 = lo + tid * 4; e0 < hi; e0 += 1024) {
        if (e0 + 3 < hi) {
            int4 s4 = *(const int4*)(src + e0);
            int4 d4 = *(const int4*)(dst + e0);
            int4 b4 = *(const int4*)(bch + e0);
            const float4* sh4 = (const float4*)(shifts + (size_t)e0 * 3);
            float4 A = sh4[0], B = sh4[1], C = sh4[2];
            int se[4] = {s4.x, s4.y, s4.z, s4.w};
            int de[4] = {d4.x, d4.y, d4.z, d4.w};
            int be[4] = {b4.x, b4.y, b4.z, b4.w};
            float sx[4] = {A.x, A.w, B.z, C.y};
            float sy[4] = {A.y, B.x, B.w, C.z};
            float sz[4] = {A.z, B.y, C.x, C.w};
#pragma unroll
            for (int k = 0; k < 4; ++k) {
                int base = be[k] * N;
                int node = base + se[k];
                const float* pd = pos + (size_t)(base + de[k]) * 3;
                const float* ps = pos + (size_t)node * 3;
                float dx = pd[0] - ps[0] + sx[k];
                float dy = pd[1] - ps[1] + sy[k];
                float dz = pd[2] - ps[2] + sz[k];
                float r = sqrtf(dx * dx + dy * dy + dz * dz);
                float pref = 2.0f * (r - 3.0f) / (r + 1e-8f);  // STRENGTH=1, CUTOFF=3
                int slot = atomicAdd(&cur[node >> 7], 1);
                float4 rec;
                rec.x = pref * dx; rec.y = pref * dy; rec.z = pref * dz;
                rec.w = __int_as_float(node);
                sorted[slot] = rec;
            }
        } else {
            for (int e = e0; e < hi; ++e) {
                int b = bch[e], s = src[e], d = dst[e];
                int base = b * N;
                int node = base + s;
                const float* pd = pos + (size_t)(base + d) * 3;
                const float* ps = pos + (size_t)node * 3;
                float dx = pd[0] - ps[0] + shifts[(size_t)e * 3 + 0];
                float dy = pd[1] - ps[1] + shifts[(size_t)e * 3 + 1];
                float dz = pd[2] - ps[2] + shifts[(size_t)e * 3 + 2];
                float r = sqrtf(dx * dx + dy * dy + dz * dz);
                float pref = 2.0f * (r - 3.0f) / (r + 1e-8f);
                int slot = atomicAdd(&cur[node >> 7], 1);
                float4 rec;
                rec.x = pref * dx; rec.y = pref * dy; rec.z = pref * dz;
                rec.w = __int_as_float(node);
                sorted[slot] = rec;
            }
        }
    }
}

// Phase D: per bucket (128 nodes), accumulate in LDS, fuse inv(basis) + residual, write out
__global__ void reduce_out_kernel(const float4* __restrict__ sorted,
                                  const int* __restrict__ ghist,
                                  const int* __restrict__ bsums,
                                  const float* __restrict__ basis,
                                  const float* __restrict__ raw,
                                  float* __restrict__ out,
                                  int E, int N, int nblk) {
    __shared__ float acc[NPB * 3];
    int tid = threadIdx.x, bkt = blockIdx.x;
    for (int i = tid; i < NPB * 3; i += 256) acc[i] = 0.0f;
    __syncthreads();
    int g0 = bkt * nblk;
    int i0 = ghist[g0] + bsums[g0 >> 10];
    int i1 = E;
    if (bkt + 1 < NCOARSE) {
        int g1 = (bkt + 1) * nblk;
        i1 = ghist[g1] + bsums[g1 >> 10];
    }
    for (int i = i0 + tid; i < i1; i += 256) {
        float4 r = sorted[i];
        int node = __float_as_int(r.w);
        int nl = node & (NPB - 1);
        atomicAdd(&acc[nl * 3 + 0], r.x);
        atomicAdd(&acc[nl * 3 + 1], r.y);
        atomicAdd(&acc[nl * 3 + 2], r.z);
    }
    __syncthreads();
    // all nodes in this bucket share one batch (NPB divides N)
    int node0 = bkt * NPB;
    int b = node0 / N;
    const float* m = basis + b * 9;
    float a00 = m[0], a01 = m[1], a02 = m[2];
    float a10 = m[3], a11 = m[4], a12 = m[5];
    float a20 = m[6], a21 = m[7], a22 = m[8];
    float c00 = a11 * a22 - a12 * a21;
    float c01 = -(a10 * a22 - a12 * a20);
    float c02 = a10 * a21 - a11 * a20;
    float det = a00 * c00 + a01 * c01 + a02 * c02;
    float id = 1.0f / det;
    float rm0 = c00 * id;
    float rm1 = (a02 * a21 - a01 * a22) * id;
    float rm2 = (a01 * a12 - a02 * a11) * id;
    float rm3 = c01 * id;
    float rm4 = (a00 * a22 - a02 * a20) * id;
    float rm5 = (a02 * a10 - a00 * a12) * id;
    float rm6 = c02 * id;
    float rm7 = (a01 * a20 - a00 * a21) * id;
    float rm8 = (a00 * a11 - a01 * a10) * id;
    for (int f = tid; f < NPB * 3; f += 256) {
        int nl = f / 3, c = f % 3;
        float x = acc[nl * 3 + 0], y = acc[nl * 3 + 1], z = acc[nl * 3 + 2];
        float rmc0 = (c == 0) ? rm0 : (c == 1) ? rm1 : rm2;
        float rmc1 = (c == 0) ? rm3 : (c == 1) ? rm4 : rm5;
        float rmc2 = (c == 0) ? rm6 : (c == 1) ? rm7 : rm8;
        size_t o = (size_t)node0 * 3 + f;
        out[o] = raw[o] + x * rmc0 + y * rmc1 + z * rmc2;
    }
}

// ---------------- fallback (device atomics, proven path) ----------------
__global__ void inv_kernel(const float* __restrict__ basis,
                           float* __restrict__ recip, int B) {
    int b = blockIdx.x * blockDim.x + threadIdx.x;
    if (b >= B) return;
    const float* m = basis + b * 9;
    float a00 = m[0], a01 = m[1], a02 = m[2];
    float a10 = m[3], a11 = m[4], a12 = m[5];
    float a20 = m[6], a21 = m[7], a22 = m[8];
    float c00 = a11 * a22 - a12 * a21;
    float c01 = -(a10 * a22 - a12 * a20);
    float c02 = a10 * a21 - a11 * a20;
    float det = a00 * c00 + a01 * c01 + a02 * c02;
    float id = 1.0f / det;
    float* r = recip + b * 9;
    r[0] = c00 * id;
    r[1] = (a02 * a21 - a01 * a22) * id;
    r[2] = (a01 * a12 - a02 * a11) * id;
    r[3] = c01 * id;
    r[4] = (a00 * a22 - a02 * a20) * id;
    r[5] = (a02 * a10 - a00 * a12) * id;
    r[6] = c02 * id;
    r[7] = (a01 * a20 - a00 * a21) * id;
    r[8] = (a00 * a11 - a01 * a10) * id;
}

__global__ void edge_kernel_dev(const float* __restrict__ pos,
                                const float* __restrict__ shifts,
                                const int* __restrict__ src,
                                const int* __restrict__ dst,
                                const int* __restrict__ bch,
                                float* __restrict__ cart,
                                int E, int N) {
    int e = blockIdx.x * blockDim.x + threadIdx.x;
    if (e >= E) return;
    int b = bch[e], s = src[e], d = dst[e];
    int base = b * N;
    const float* pd = pos + (size_t)(base + d) * 3;
    const float* ps = pos + (size_t)(base + s) * 3;
    float dx = pd[0] - ps[0] + shifts[(size_t)e * 3 + 0];
    float dy = pd[1] - ps[1] + shifts[(size_t)e * 3 + 1];
    float dz = pd[2] - ps[2] + shifts[(size_t)e * 3 + 2];
    float r = sqrtf(dx * dx + dy * dy + dz * dz);
    float pref = 2.0f * (r - 3.0f) / (r + 1e-8f);
    float* c = cart + (size_t)(base + s) * 3;
    atomicAdd(&c[0], pref * dx);
    atomicAdd(&c[1], pref * dy);
    atomicAdd(&c[2], pref * dz);
}

__global__ void out_kernel(const float* __restrict__ cart,
                           const float* __restrict__ recip,
                           const float* __restrict__ raw,
                           float* __restrict__ out,
                           int BN, int N) {
    int idx = blockIdx.x * blockDim.x + threadIdx.x;
    if (idx >= BN) return;
    int b = idx / N;
    const float* rm = recip + b * 9;
    float x = cart[idx * 3 + 0], y = cart[idx * 3 + 1], z = cart[idx * 3 + 2];
    out[idx * 3 + 0] = raw[idx * 3 + 0] + x * rm[0] + y * rm[3] + z * rm[6];
    out[idx * 3 + 1] = raw[idx * 3 + 1] + x * rm[1] + y * rm[4] + z * rm[7];
    out[idx * 3 + 2] = raw[idx * 3 + 2] + x * rm[2] + y * rm[5] + z * rm[8];
}

template <int NBLK>
static void run_fast(const float* rel, const float* basis, const float* shifts,
                     const float* raw, const int* src, const int* dst, const int* bch,
                     float* out, void* d_ws, int B, int BN, int N, int E,
                     hipStream_t stream) {
    float4* sorted = (float4*)d_ws;
    float*  pos    = (float*)(sorted + E);
    int*    ghist  = (int*)(pos + (size_t)BN * 3);
    int*    bsums  = ghist + NCOARSE * NBLK;
    // chunk: multiple of 4 so int4/float4 loads stay aligned
    int chunk = ((E + NBLK - 1) / NBLK + 3) & ~3;

    pos_kernel<<<(BN + 255) / 256, 256, 0, stream>>>(rel, basis, pos, BN, N);
    hist_kernel<NBLK><<<NBLK, 256, 0, stream>>>(src, bch, ghist, E, N, chunk);
    scan1_kernel<<<NCOARSE * NBLK / SCAN_BS, 256, 0, stream>>>(ghist, bsums);
    scan2_kernel<<<1, 1024, 0, stream>>>(bsums, NCOARSE * NBLK / SCAN_BS);
    scatter_kernel<NBLK><<<NBLK, 256, 0, stream>>>(pos, shifts, src, dst, bch,
                                                   ghist, bsums, sorted, E, N, chunk);
    reduce_out_kernel<<<NCOARSE, 256, 0, stream>>>(sorted, ghist, bsums, basis,
                                                   raw, out, E, N, NBLK);
}

extern "C" void kernel_launch(void* const* d_in, const int* in_sizes, int n_in,
                              void* d_out, int out_size, void* d_ws, size_t ws_size,
                              hipStream_t stream) {
    const float* rel    = (const float*)d_in[0];
    const float* basis  = (const float*)d_in[1];
    const float* shifts = (const float*)d_in[2];
    const float* raw    = (const float*)d_in[3];
    const int*   src    = (const int*)d_in[4];
    const int*   dst    = (const int*)d_in[5];
    const int*   bch    = (const int*)d_in[6];

    int B  = in_sizes[1] / 9;
    int BN = in_sizes[0] / 3;
    int N  = BN / B;
    int E  = in_sizes[4];

    size_t base_need = (size_t)E * 16 + (size_t)BN * 3 * 4;
    size_t need2048  = base_need + ((size_t)NCOARSE * 2048 + SCAN_BS) * 4;
    size_t need1024  = base_need + ((size_t)NCOARSE * 1024 + SCAN_BS) * 4;
    bool geom_ok = (BN == NCOARSE * NPB) && (N % NPB == 0);

    if (geom_ok && ws_size >= need2048) {
        run_fast<2048>(rel, basis, shifts, raw, src, dst, bch,
                       (float*)d_out, d_ws, B, BN, N, E, stream);
    } else if (geom_ok && ws_size >= need1024) {
        run_fast<1024>(rel, basis, shifts, raw, src, dst, bch,
                       (float*)d_out, d_ws, B, BN, N, E, stream);
    } else {
        // fallback: device-scope atomics (known-good, ~315 us)
        float* pos   = (float*)d_ws;
        float* cart  = pos + (size_t)BN * 3;
        float* recip = cart + (size_t)BN * 3;
        hipMemsetAsync(cart, 0, (size_t)BN * 3 * sizeof(float), stream);
        pos_kernel<<<(BN + 255) / 256, 256, 0, stream>>>(rel, basis, pos, BN, N);
        inv_kernel<<<1, 64, 0, stream>>>(basis, recip, B);
        edge_kernel_dev<<<(E + 255) / 256, 256, 0, stream>>>(pos, shifts, src, dst, bch,
                                                             cart, E, N);
        out_kernel<<<(BN + 255) / 256, 256, 0, stream>>>(cart, recip, raw,
                                                         (float*)d_out, BN, N);
    }
}

// Round 7
// 92.910 us; speedup vs baseline: 1.0896x; 1.0896x over previous
//
#include <hip/hip_runtime.h>

// ---- fast-path geometry ----
#define NBLK    2048       // hist/scatter blocks
#define NBUK    16         // max batches (bucket = batch index)
#define MAXN    4096       // max nodes/batch for 48 KB LDS accumulator
#define SCAN_N  (NBUK * NBLK)   // 32768 ghist entries
#define SCAN_BS 1024

// pos4[b*N+n] = cartesian position (padded float4 -> single dwordx4 gathers)
__global__ void pos_kernel(const float* __restrict__ rel,
                           const float* __restrict__ basis,
                           float4* __restrict__ pos4,
                           int BN, int N) {
    int idx = blockIdx.x * blockDim.x + threadIdx.x;
    if (idx >= BN) return;
    int b = idx / N;
    const float* bm = basis + b * 9;
    float x = rel[idx * 3 + 0], y = rel[idx * 3 + 1], z = rel[idx * 3 + 2];
    float4 p;
    p.x = x * bm[0] + y * bm[3] + z * bm[6];
    p.y = x * bm[1] + y * bm[4] + z * bm[7];
    p.z = x * bm[2] + y * bm[5] + z * bm[8];
    p.w = 0.0f;
    pos4[idx] = p;
}

// per-batch 3x3 inverse (adjugate / det)
__global__ void inv_kernel(const float* __restrict__ basis,
                           float* __restrict__ recip, int B) {
    int b = blockIdx.x * blockDim.x + threadIdx.x;
    if (b >= B) return;
    const float* m = basis + b * 9;
    float a00 = m[0], a01 = m[1], a02 = m[2];
    float a10 = m[3], a11 = m[4], a12 = m[5];
    float a20 = m[6], a21 = m[7], a22 = m[8];
    float c00 = a11 * a22 - a12 * a21;
    float c01 = -(a10 * a22 - a12 * a20);
    float c02 = a10 * a21 - a11 * a20;
    float det = a00 * c00 + a01 * c01 + a02 * c02;
    float id = 1.0f / det;
    float* r = recip + b * 9;
    r[0] = c00 * id;
    r[1] = (a02 * a21 - a01 * a22) * id;
    r[2] = (a01 * a12 - a02 * a11) * id;
    r[3] = c01 * id;
    r[4] = (a00 * a22 - a02 * a20) * id;
    r[5] = (a02 * a10 - a00 * a12) * id;
    r[6] = c02 * id;
    r[7] = (a01 * a20 - a00 * a21) * id;
    r[8] = (a00 * a11 - a01 * a10) * id;
}

// Phase A: per-block histogram over B batch-buckets -> ghist[buk*NBLK + blk]
__global__ void hist_kernel(const int* __restrict__ bch,
                            int* __restrict__ ghist,
                            int E, int chunk) {
    __shared__ int h[NBUK];
    int tid = threadIdx.x, blk = blockIdx.x;
    if (tid < NBUK) h[tid] = 0;
    __syncthreads();
    int lo = blk * chunk, hi = min(E, lo + chunk);
    for (int e0 = lo + tid * 4; e0 < hi; e0 += 1024) {
        if (e0 + 3 < hi) {
            int4 b4 = *(const int4*)(bch + e0);
            atomicAdd(&h[b4.x], 1);
            atomicAdd(&h[b4.y], 1);
            atomicAdd(&h[b4.z], 1);
            atomicAdd(&h[b4.w], 1);
        } else {
            for (int e = e0; e < hi; ++e) atomicAdd(&h[bch[e]], 1);
        }
    }
    __syncthreads();
    if (tid < NBUK) ghist[tid * NBLK + blk] = h[tid];
}

// Phase B1: scan 1024-element tiles (exclusive, in place), emit tile sums
__global__ void scan1_kernel(int* __restrict__ g, int* __restrict__ bsums) {
    __shared__ int tp[256];
    int tid = threadIdx.x;
    int base = blockIdx.x * SCAN_BS + tid * 4;
    int v0 = g[base], v1 = g[base + 1], v2 = g[base + 2], v3 = g[base + 3];
    int s = v0 + v1 + v2 + v3;
    tp[tid] = s;
    for (int off = 1; off < 256; off <<= 1) {
        __syncthreads();
        int t = (tid >= off) ? tp[tid - off] : 0;
        __syncthreads();
        tp[tid] += t;
    }
    __syncthreads();
    int incl = tp[tid];
    int excl = incl - s;
    g[base]     = excl;
    g[base + 1] = excl + v0;
    g[base + 2] = excl + v0 + v1;
    g[base + 3] = excl + v0 + v1 + v2;
    if (tid == 255) bsums[blockIdx.x] = incl;
}

// Phase B2: exclusive scan of tile sums (n <= 1024), one block
__global__ void scan2_kernel(int* __restrict__ bsums, int n) {
    __shared__ int tp[1024];
    int tid = threadIdx.x;
    int v = (tid < n) ? bsums[tid] : 0;
    tp[tid] = v;
    for (int off = 1; off < 1024; off <<= 1) {
        __syncthreads();
        int t = (tid >= off) ? tp[tid - off] : 0;
        __syncthreads();
        tp[tid] += t;
    }
    __syncthreads();
    if (tid < n) bsums[tid] = tp[tid] - v;
}

// Phase C: compute contribution, write record (fx,fy,fz,local_node) into batch region
__global__ void scatter_kernel(const float4* __restrict__ pos4,
                               const float* __restrict__ shifts,
                               const int* __restrict__ src,
                               const int* __restrict__ dst,
                               const int* __restrict__ bch,
                               const int* __restrict__ ghist,
                               const int* __restrict__ bsums,
                               float4* __restrict__ recs,
                               int E, int N, int chunk) {
    __shared__ int cur[NBUK];
    int tid = threadIdx.x, blk = blockIdx.x;
    if (tid < NBUK) {
        int idx = tid * NBLK + blk;
        cur[tid] = ghist[idx] + bsums[idx >> 10];
    }
    __syncthreads();
    int lo = blk * chunk, hi = min(E, lo + chunk);
    for (int e0 = lo + tid * 4; e0 < hi; e0 += 1024) {
        if (e0 + 3 < hi) {
            int4 s4 = *(const int4*)(src + e0);
            int4 d4 = *(const int4*)(dst + e0);
            int4 b4 = *(const int4*)(bch + e0);
            const float4* sh4 = (const float4*)(shifts + (size_t)e0 * 3);
            float4 A = sh4[0], Bv = sh4[1], C = sh4[2];
            int se[4] = {s4.x, s4.y, s4.z, s4.w};
            int de[4] = {d4.x, d4.y, d4.z, d4.w};
            int be[4] = {b4.x, b4.y, b4.z, b4.w};
            float sx[4] = {A.x, A.w, Bv.z, C.y};
            float sy[4] = {A.y, Bv.x, Bv.w, C.z};
            float sz[4] = {A.z, Bv.y, C.x, C.w};
#pragma unroll
            for (int k = 0; k < 4; ++k) {
                int base = be[k] * N;
                float4 P = pos4[base + de[k]];
                float4 Q = pos4[base + se[k]];
                float dx = P.x - Q.x + sx[k];
                float dy = P.y - Q.y + sy[k];
                float dz = P.z - Q.z + sz[k];
                float r = sqrtf(dx * dx + dy * dy + dz * dz);
                float pref = 2.0f * (r - 3.0f) / (r + 1e-8f);  // STRENGTH=1, CUTOFF=3
                int slot = atomicAdd(&cur[be[k]], 1);
                float4 rec;
                rec.x = pref * dx; rec.y = pref * dy; rec.z = pref * dz;
                rec.w = __int_as_float(se[k]);   // local node id within batch
                recs[slot] = rec;
            }
        } else {
            for (int e = e0; e < hi; ++e) {
                int b = bch[e], s = src[e], d = dst[e];
                int base = b * N;
                float4 P = pos4[base + d];
                float4 Q = pos4[base + s];
                float dx = P.x - Q.x + shifts[(size_t)e * 3 + 0];
                float dy = P.y - Q.y + shifts[(size_t)e * 3 + 1];
                float dz = P.z - Q.z + shifts[(size_t)e * 3 + 2];
                float r = sqrtf(dx * dx + dy * dy + dz * dz);
                float pref = 2.0f * (r - 3.0f) / (r + 1e-8f);
                int slot = atomicAdd(&cur[b], 1);
                float4 rec;
                rec.x = pref * dx; rec.y = pref * dy; rec.z = pref * dz;
                rec.w = __int_as_float(s);
                recs[slot] = rec;
            }
        }
    }
}

// Phase D: LDS-accumulate a slice of one batch's records -> 48 KB partial
__global__ void accum_kernel(const float4* __restrict__ recs,
                             const int* __restrict__ ghist,
                             const int* __restrict__ bsums,
                             float* __restrict__ partials,
                             int E, int N, int B, int PPB) {
    __shared__ float acc[MAXN * 3];
    int bx = blockIdx.x;
    int b = bx / PPB, p = bx % PPB;
    int tid = threadIdx.x;
    int n3 = N * 3;
    for (int i = tid * 4; i < n3; i += 1024)
        *(float4*)&acc[i] = make_float4(0.f, 0.f, 0.f, 0.f);
    __syncthreads();
    int g0 = b * NBLK;
    int i0 = ghist[g0] + bsums[g0 >> 10];
    int i1 = E;
    if (b + 1 < NBUK) {
        int g1 = (b + 1) * NBLK;
        i1 = ghist[g1] + bsums[g1 >> 10];
    }
    long long len = (long long)(i1 - i0);
    int lo = i0 + (int)(len * p / PPB);
    int hi = i0 + (int)(len * (p + 1) / PPB);
    for (int i = lo + tid; i < hi; i += 256) {
        float4 r = recs[i];
        int nl = __float_as_int(r.w);
        atomicAdd(&acc[nl * 3 + 0], r.x);
        atomicAdd(&acc[nl * 3 + 1], r.y);
        atomicAdd(&acc[nl * 3 + 2], r.z);
    }
    __syncthreads();
    float* dstp = partials + (size_t)bx * n3;
    for (int i = tid * 4; i < n3; i += 1024)
        *(float4*)&dstp[i] = *(const float4*)&acc[i];
}

// Phase E: sum PPB partials per node, transform to relative, add raw
__global__ void final_kernel(const float* __restrict__ partials,
                             const float* __restrict__ recip,
                             const float* __restrict__ raw,
                             float* __restrict__ out,
                             int BN, int N, int PPB) {
    int idx = blockIdx.x * blockDim.x + threadIdx.x;
    if (idx >= BN) return;
    int b = idx / N;
    int nl = idx - b * N;
    int n3 = N * 3;
    const float* pp = partials + ((size_t)b * PPB) * n3 + (size_t)nl * 3;
    float x = 0.f, y = 0.f, z = 0.f;
    for (int p = 0; p < PPB; ++p) {
        x += pp[0]; y += pp[1]; z += pp[2];
        pp += n3;
    }
    const float* rm = recip + b * 9;
    out[idx * 3 + 0] = raw[idx * 3 + 0] + x * rm[0] + y * rm[3] + z * rm[6];
    out[idx * 3 + 1] = raw[idx * 3 + 1] + x * rm[1] + y * rm[4] + z * rm[7];
    out[idx * 3 + 2] = raw[idx * 3 + 2] + x * rm[2] + y * rm[5] + z * rm[8];
}

// ---------------- fallback (device atomics, known-good ~315 us) ----------------
__global__ void pos3_kernel(const float* __restrict__ rel,
                            const float* __restrict__ basis,
                            float* __restrict__ pos,
                            int BN, int N) {
    int idx = blockIdx.x * blockDim.x + threadIdx.x;
    if (idx >= BN) return;
    int b = idx / N;
    const float* bm = basis + b * 9;
    float x = rel[idx * 3 + 0], y = rel[idx * 3 + 1], z = rel[idx * 3 + 2];
    pos[idx * 3 + 0] = x * bm[0] + y * bm[3] + z * bm[6];
    pos[idx * 3 + 1] = x * bm[1] + y * bm[4] + z * bm[7];
    pos[idx * 3 + 2] = x * bm[2] + y * bm[5] + z * bm[8];
}

__global__ void edge_kernel_dev(const float* __restrict__ pos,
                                const float* __restrict__ shifts,
                                const int* __restrict__ src,
                                const int* __restrict__ dst,
                                const int* __restrict__ bch,
                                float* __restrict__ cart,
                                int E, int N) {
    int e = blockIdx.x * blockDim.x + threadIdx.x;
    if (e >= E) return;
    int b = bch[e], s = src[e], d = dst[e];
    int base = b * N;
    const float* pd = pos + (size_t)(base + d) * 3;
    const float* ps = pos + (size_t)(base + s) * 3;
    float dx = pd[0] - ps[0] + shifts[(size_t)e * 3 + 0];
    float dy = pd[1] - ps[1] + shifts[(size_t)e * 3 + 1];
    float dz = pd[2] - ps[2] + shifts[(size_t)e * 3 + 2];
    float r = sqrtf(dx * dx + dy * dy + dz * dz);
    float pref = 2.0f * (r - 3.0f) / (r + 1e-8f);
    float* c = cart + (size_t)(base + s) * 3;
    atomicAdd(&c[0], pref * dx);
    atomicAdd(&c[1], pref * dy);
    atomicAdd(&c[2], pref * dz);
}

__global__ void out_kernel(const float* __restrict__ cart,
                           const float* __restrict__ recip,
                           const float* __restrict__ raw,
                           float* __restrict__ out,
                           int BN, int N) {
    int idx = blockIdx.x * blockDim.x + threadIdx.x;
    if (idx >= BN) return;
    int b = idx / N;
    const float* rm = recip + b * 9;
    float x = cart[idx * 3 + 0], y = cart[idx * 3 + 1], z = cart[idx * 3 + 2];
    out[idx * 3 + 0] = raw[idx * 3 + 0] + x * rm[0] + y * rm[3] + z * rm[6];
    out[idx * 3 + 1] = raw[idx * 3 + 1] + x * rm[1] + y * rm[4] + z * rm[7];
    out[idx * 3 + 2] = raw[idx * 3 + 2] + x * rm[2] + y * rm[5] + z * rm[8];
}

extern "C" void kernel_launch(void* const* d_in, const int* in_sizes, int n_in,
                              void* d_out, int out_size, void* d_ws, size_t ws_size,
                              hipStream_t stream) {
    const float* rel    = (const float*)d_in[0];
    const float* basis  = (const float*)d_in[1];
    const float* shifts = (const float*)d_in[2];
    const float* raw    = (const float*)d_in[3];
    const int*   src    = (const int*)d_in[4];
    const int*   dst    = (const int*)d_in[5];
    const int*   bch    = (const int*)d_in[6];

    int B  = in_sizes[1] / 9;
    int BN = in_sizes[0] / 3;
    int N  = BN / B;
    int E  = in_sizes[4];

    // fast-path ws layout: recs[E] f4 | pos4[BN] f4 | ghist[SCAN_N] | bsums[32] | recip[144] | partials
    char* w = (char*)d_ws;
    float4* recs  = (float4*)w;  w += (size_t)E * 16;
    float4* pos4  = (float4*)w;  w += (size_t)BN * 16;
    int*    ghist = (int*)w;     w += (size_t)SCAN_N * 4;
    int*    bsums = (int*)w;     w += 32 * 4;
    float*  recip = (float*)w;   w += 144 * 4;
    float*  partials = (float*)w;
    size_t base_bytes = (size_t)(w - (char*)d_ws);

    bool geom_ok = (B >= 1) && (B <= NBUK) && (N >= 4) && (N <= MAXN) &&
                   ((N * 3) % 4 == 0) && (BN == B * N) && (E >= 4);
    size_t per_ppb = (size_t)B * N * 3 * 4;
    int PPB = 0;
    if (geom_ok && ws_size > base_bytes)
        PPB = (int)((ws_size - base_bytes) / per_ppb);
    if (PPB > 32) PPB = 32;

    if (geom_ok && PPB >= 2) {
        int chunk = ((E + NBLK - 1) / NBLK + 3) & ~3;
        pos_kernel<<<(BN + 255) / 256, 256, 0, stream>>>(rel, basis, pos4, BN, N);
        inv_kernel<<<1, 64, 0, stream>>>(basis, recip, B);
        hist_kernel<<<NBLK, 256, 0, stream>>>(bch, ghist, E, chunk);
        scan1_kernel<<<SCAN_N / SCAN_BS, 256, 0, stream>>>(ghist, bsums);
        scan2_kernel<<<1, 1024, 0, stream>>>(bsums, SCAN_N / SCAN_BS);
        scatter_kernel<<<NBLK, 256, 0, stream>>>(pos4, shifts, src, dst, bch,
                                                 ghist, bsums, recs, E, N, chunk);
        accum_kernel<<<B * PPB, 256, 0, stream>>>(recs, ghist, bsums, partials,
                                                  E, N, B, PPB);
        final_kernel<<<(BN + 255) / 256, 256, 0, stream>>>(partials, recip, raw,
                                                           (float*)d_out, BN, N, PPB);
    } else {
        // fallback: device-scope atomics
        float* pos  = (float*)d_ws;
        float* cart = pos + (size_t)BN * 3;
        float* rcp  = cart + (size_t)BN * 3;
        hipMemsetAsync(cart, 0, (size_t)BN * 3 * sizeof(float), stream);
        pos3_kernel<<<(BN + 255) / 256, 256, 0, stream>>>(rel, basis, pos, BN, N);
        inv_kernel<<<1, 64, 0, stream>>>(basis, rcp, B);
        edge_kernel_dev<<<(E + 255) / 256, 256, 0, stream>>>(pos, shifts, src, dst, bch,
                                                             cart, E, N);
        out_kernel<<<(BN + 255) / 256, 256, 0, stream>>>(cart, rcp, raw,
                                                         (float*)d_out, BN, N);
    }
}

// Round 9
// 82.914 us; speedup vs baseline: 1.2210x; 1.1206x over previous
//
#include <hip/hip_runtime.h>

// ---- fast-path geometry ----
#define NBLK 2048              // hist/scatter blocks
#define NBUK 16                // max batches (bucket = batch)
#define MAXN 4096              // max nodes/batch (48 KB LDS accumulator, 12-bit packing)
#define SCAN_N (NBUK * NBLK)   // 32768 ghist entries

// K1: blocks [0,PB): pos4[idx] = rel@basis (padded float4); blocks [PB,PB+NBLK): batch histogram
__global__ void prep_kernel(const float* __restrict__ rel,
                            const float* __restrict__ basis,
                            const int* __restrict__ bch,
                            float4* __restrict__ pos4,
                            int* __restrict__ ghist,
                            int BN, int N, int E, int chunk, int PB) {
    int blk = blockIdx.x, tid = threadIdx.x;
    if (blk < PB) {
        int idx = blk * 256 + tid;
        if (idx < BN) {
            int b = idx / N;
            const float* bm = basis + b * 9;
            float x = rel[idx * 3 + 0], y = rel[idx * 3 + 1], z = rel[idx * 3 + 2];
            float4 p;
            p.x = x * bm[0] + y * bm[3] + z * bm[6];
            p.y = x * bm[1] + y * bm[4] + z * bm[7];
            p.z = x * bm[2] + y * bm[5] + z * bm[8];
            p.w = 0.0f;
            pos4[idx] = p;
        }
        return;
    }
    __shared__ int h[NBUK];
    int hb = blk - PB;
    if (tid < NBUK) h[tid] = 0;
    __syncthreads();
    int lo = hb * chunk, hi = min(E, lo + chunk);
    for (int e0 = lo + tid * 4; e0 < hi; e0 += 1024) {
        if (e0 + 3 < hi) {
            int4 b4 = *(const int4*)(bch + e0);
            atomicAdd(&h[b4.x], 1);
            atomicAdd(&h[b4.y], 1);
            atomicAdd(&h[b4.z], 1);
            atomicAdd(&h[b4.w], 1);
        } else {
            for (int e = e0; e < hi; ++e) atomicAdd(&h[bch[e]], 1);
        }
    }
    __syncthreads();
    if (tid < NBUK) ghist[tid * NBLK + hb] = h[tid];
}

// K2: exclusive scan of all SCAN_N entries, single block of 1024 (32 entries/thread)
__global__ void scan_kernel(int* __restrict__ g) {
    __shared__ int tp[1024];
    int tid = threadIdx.x;
    int base = tid * 32;
    int v[32];
    int s = 0;
#pragma unroll
    for (int i = 0; i < 8; ++i) {
        int4 q = *(const int4*)(g + base + i * 4);
        v[i * 4 + 0] = q.x; v[i * 4 + 1] = q.y;
        v[i * 4 + 2] = q.z; v[i * 4 + 3] = q.w;
        s += q.x + q.y + q.z + q.w;
    }
    tp[tid] = s;
    for (int off = 1; off < 1024; off <<= 1) {
        __syncthreads();
        int t = (tid >= off) ? tp[tid - off] : 0;
        __syncthreads();
        tp[tid] += t;
    }
    __syncthreads();
    int run = tp[tid] - s;  // exclusive base
#pragma unroll
    for (int i = 0; i < 8; ++i) {
        int4 q;
        q.x = run; run += v[i * 4 + 0];
        q.y = run; run += v[i * 4 + 1];
        q.z = run; run += v[i * 4 + 2];
        q.w = run; run += v[i * 4 + 3];
        *(int4*)(g + base + i * 4) = q;
    }
}

// K3: pure reorder — record = (shift.xyz, src|dst<<12) grouped by batch. No gathers, no math.
__global__ void scatter_kernel(const float* __restrict__ shifts,
                               const int* __restrict__ src,
                               const int* __restrict__ dst,
                               const int* __restrict__ bch,
                               const int* __restrict__ ghist,
                               float4* __restrict__ recs,
                               int E, int chunk) {
    __shared__ int cur[NBUK];
    int tid = threadIdx.x, blk = blockIdx.x;
    if (tid < NBUK) cur[tid] = ghist[tid * NBLK + blk];
    __syncthreads();
    int lo = blk * chunk, hi = min(E, lo + chunk);
    for (int e0 = lo + tid * 4; e0 < hi; e0 += 1024) {
        if (e0 + 3 < hi) {
            int4 s4 = *(const int4*)(src + e0);
            int4 d4 = *(const int4*)(dst + e0);
            int4 b4 = *(const int4*)(bch + e0);
            const float4* sh4 = (const float4*)(shifts + (size_t)e0 * 3);
            float4 A = sh4[0], Bv = sh4[1], C = sh4[2];
            int se[4] = {s4.x, s4.y, s4.z, s4.w};
            int de[4] = {d4.x, d4.y, d4.z, d4.w};
            int be[4] = {b4.x, b4.y, b4.z, b4.w};
            float sx[4] = {A.x, A.w, Bv.z, C.y};
            float sy[4] = {A.y, Bv.x, Bv.w, C.z};
            float sz[4] = {A.z, Bv.y, C.x, C.w};
#pragma unroll
            for (int k = 0; k < 4; ++k) {
                int slot = atomicAdd(&cur[be[k]], 1);
                float4 rec;
                rec.x = sx[k]; rec.y = sy[k]; rec.z = sz[k];
                rec.w = __int_as_float(se[k] | (de[k] << 12));
                recs[slot] = rec;
            }
        } else {
            for (int e = e0; e < hi; ++e) {
                int slot = atomicAdd(&cur[bch[e]], 1);
                float4 rec;
                rec.x = shifts[(size_t)e * 3 + 0];
                rec.y = shifts[(size_t)e * 3 + 1];
                rec.z = shifts[(size_t)e * 3 + 2];
                rec.w = __int_as_float(src[e] | (dst[e] << 12));
                recs[slot] = rec;
            }
        }
    }
}

// K4: per (batch, slice): gather pos (L1/L2-hot 64 KB slice), compute force, LDS-accumulate
__global__ void accum_kernel(const float4* __restrict__ recs,
                             const float4* __restrict__ pos4,
                             const int* __restrict__ ghist,
                             float* __restrict__ partials,
                             int E, int N, int PPB) {
    __shared__ float acc[MAXN * 3];
    int bx = blockIdx.x;
    int b = bx / PPB, p = bx % PPB;
    int tid = threadIdx.x;
    int n3 = N * 3;
    for (int i = tid * 4; i < n3; i += 1024)
        *(float4*)&acc[i] = make_float4(0.f, 0.f, 0.f, 0.f);
    __syncthreads();
    int i0 = ghist[b * NBLK];
    int i1 = (b + 1 < NBUK) ? ghist[(b + 1) * NBLK] : E;
    const float4* pb = pos4 + (size_t)b * N;
    long long len = (long long)(i1 - i0);
    int lo = i0 + (int)(len * p / PPB);
    int hi = i0 + (int)(len * (p + 1) / PPB);
    for (int i = lo + tid; i < hi; i += 256) {
        float4 r = recs[i];
        int u = __float_as_int(r.w);
        int s = u & 4095, d = (u >> 12) & 4095;
        float4 P = pb[d], Q = pb[s];
        float dx = P.x - Q.x + r.x;
        float dy = P.y - Q.y + r.y;
        float dz = P.z - Q.z + r.z;
        float rr = sqrtf(dx * dx + dy * dy + dz * dz);
        float pref = 2.0f * (rr - 3.0f) / (rr + 1e-8f);  // STRENGTH=1, CUTOFF=3
        atomicAdd(&acc[s * 3 + 0], pref * dx);
        atomicAdd(&acc[s * 3 + 1], pref * dy);
        atomicAdd(&acc[s * 3 + 2], pref * dz);
    }
    __syncthreads();
    float* dstp = partials + (size_t)bx * n3;
    for (int i = tid * 4; i < n3; i += 1024)
        *(float4*)&dstp[i] = *(const float4*)&acc[i];
}

// K5: sum PPB partials (coalesced), fold 3x3 inverse, transform + residual
__global__ void final_kernel(const float* __restrict__ partials,
                             const float* __restrict__ basis,
                             const float* __restrict__ raw,
                             float* __restrict__ out,
                             int BN, int N, int PPB) {
    int idx = blockIdx.x * blockDim.x + threadIdx.x;
    if (idx >= BN) return;
    int b = idx / N;
    int nl = idx - b * N;
    int n3 = N * 3;
    const float* pp = partials + (size_t)b * PPB * n3 + (size_t)nl * 3;
    float x = 0.f, y = 0.f, z = 0.f;
    for (int p = 0; p < PPB; ++p) {
        x += pp[0]; y += pp[1]; z += pp[2];
        pp += n3;
    }
    const float* m = basis + b * 9;
    float a00 = m[0], a01 = m[1], a02 = m[2];
    float a10 = m[3], a11 = m[4], a12 = m[5];
    float a20 = m[6], a21 = m[7], a22 = m[8];
    float c00 = a11 * a22 - a12 * a21;
    float c01 = -(a10 * a22 - a12 * a20);
    float c02 = a10 * a21 - a11 * a20;
    float det = a00 * c00 + a01 * c01 + a02 * c02;
    float id = 1.0f / det;
    float rm0 = c00 * id;
    float rm1 = (a02 * a21 - a01 * a22) * id;
    float rm2 = (a01 * a12 - a02 * a11) * id;
    float rm3 = c01 * id;
    float rm4 = (a00 * a22 - a02 * a20) * id;
    float rm5 = (a02 * a10 - a00 * a12) * id;
    float rm6 = c02 * id;
    float rm7 = (a01 * a20 - a00 * a21) * id;
    float rm8 = (a00 * a11 - a01 * a10) * id;
    out[idx * 3 + 0] = raw[idx * 3 + 0] + x * rm0 + y * rm3 + z * rm6;
    out[idx * 3 + 1] = raw[idx * 3 + 1] + x * rm1 + y * rm4 + z * rm7;
    out[idx * 3 + 2] = raw[idx * 3 + 2] + x * rm2 + y * rm5 + z * rm8;
}

// ---------------- fallback (device atomics, known-good ~315 us) ----------------
__global__ void pos3_kernel(const float* __restrict__ rel,
                            const float* __restrict__ basis,
                            float* __restrict__ pos,
                            int BN, int N) {
    int idx = blockIdx.x * blockDim.x + threadIdx.x;
    if (idx >= BN) return;
    int b = idx / N;
    const float* bm = basis + b * 9;
    float x = rel[idx * 3 + 0], y = rel[idx * 3 + 1], z = rel[idx * 3 + 2];
    pos[idx * 3 + 0] = x * bm[0] + y * bm[3] + z * bm[6];
    pos[idx * 3 + 1] = x * bm[1] + y * bm[4] + z * bm[7];
    pos[idx * 3 + 2] = x * bm[2] + y * bm[5] + z * bm[8];
}

__global__ void inv_kernel(const float* __restrict__ basis,
                           float* __restrict__ recip, int B) {
    int b = blockIdx.x * blockDim.x + threadIdx.x;
    if (b >= B) return;
    const float* m = basis + b * 9;
    float a00 = m[0], a01 = m[1], a02 = m[2];
    float a10 = m[3], a11 = m[4], a12 = m[5];
    float a20 = m[6], a21 = m[7], a22 = m[8];
    float c00 = a11 * a22 - a12 * a21;
    float c01 = -(a10 * a22 - a12 * a20);
    float c02 = a10 * a21 - a11 * a20;
    float det = a00 * c00 + a01 * c01 + a02 * c02;
    float id = 1.0f / det;
    float* r = recip + b * 9;
    r[0] = c00 * id;
    r[1] = (a02 * a21 - a01 * a22) * id;
    r[2] = (a01 * a12 - a02 * a11) * id;
    r[3] = c01 * id;
    r[4] = (a00 * a22 - a02 * a20) * id;
    r[5] = (a02 * a10 - a00 * a12) * id;
    r[6] = c02 * id;
    r[7] = (a01 * a20 - a00 * a21) * id;
    r[8] = (a00 * a11 - a01 * a10) * id;
}

__global__ void edge_kernel_dev(const float* __restrict__ pos,
                                const float* __restrict__ shifts,
                                const int* __restrict__ src,
                                const int* __restrict__ dst,
                                const int* __restrict__ bch,
                                float* __restrict__ cart,
                                int E, int N) {
    int e = blockIdx.x * blockDim.x + threadIdx.x;
    if (e >= E) return;
    int b = bch[e], s = src[e], d = dst[e];
    int base = b * N;
    const float* pd = pos + (size_t)(base + d) * 3;
    const float* ps = pos + (size_t)(base + s) * 3;
    float dx = pd[0] - ps[0] + shifts[(size_t)e * 3 + 0];
    float dy = pd[1] - ps[1] + shifts[(size_t)e * 3 + 1];
    float dz = pd[2] - ps[2] + shifts[(size_t)e * 3 + 2];
    float r = sqrtf(dx * dx + dy * dy + dz * dz);
    float pref = 2.0f * (r - 3.0f) / (r + 1e-8f);
    float* c = cart + (size_t)(base + s) * 3;
    atomicAdd(&c[0], pref * dx);
    atomicAdd(&c[1], pref * dy);
    atomicAdd(&c[2], pref * dz);
}

__global__ void out_kernel(const float* __restrict__ cart,
                           const float* __restrict__ recip,
                           const float* __restrict__ raw,
                           float* __restrict__ out,
                           int BN, int N) {
    int idx = blockIdx.x * blockDim.x + threadIdx.x;
    if (idx >= BN) return;
    int b = idx / N;
    const float* rm = recip + b * 9;
    float x = cart[idx * 3 + 0], y = cart[idx * 3 + 1], z = cart[idx * 3 + 2];
    out[idx * 3 + 0] = raw[idx * 3 + 0] + x * rm[0] + y * rm[3] + z * rm[6];
    out[idx * 3 + 1] = raw[idx * 3 + 1] + x * rm[1] + y * rm[4] + z * rm[7];
    out[idx * 3 + 2] = raw[idx * 3 + 2] + x * rm[2] + y * rm[5] + z * rm[8];
}

extern "C" void kernel_launch(void* const* d_in, const int* in_sizes, int n_in,
                              void* d_out, int out_size, void* d_ws, size_t ws_size,
                              hipStream_t stream) {
    const float* rel    = (const float*)d_in[0];
    const float* basis  = (const float*)d_in[1];
    const float* shifts = (const float*)d_in[2];
    const float* raw    = (const float*)d_in[3];
    const int*   src    = (const int*)d_in[4];
    const int*   dst    = (const int*)d_in[5];
    const int*   bch    = (const int*)d_in[6];

    int B  = in_sizes[1] / 9;
    int BN = in_sizes[0] / 3;
    int N  = BN / B;
    int E  = in_sizes[4];

    // ws layout: recs[E] f4 | pos4[BN] f4 | ghist[SCAN_N] i32 | partials[B*PPB*N*3] f32
    char* w = (char*)d_ws;
    float4* recs  = (float4*)w;  w += (size_t)E * 16;
    float4* pos4  = (float4*)w;  w += (size_t)BN * 16;
    int*    ghist = (int*)w;     w += (size_t)SCAN_N * 4;
    float*  partials = (float*)w;
    size_t base_bytes = (size_t)(w - (char*)d_ws);

    bool geom_ok = (B >= 1) && (B <= NBUK) && (N >= 4) && (N <= MAXN) &&
                   (N % 4 == 0) && (BN == B * N) && (E >= 4);
    size_t per_ppb = (size_t)B * N * 3 * 4;
    int PPB = 0;
    if (geom_ok && ws_size > base_bytes)
        PPB = (int)((ws_size - base_bytes) / per_ppb);
    if (PPB > 32) PPB = 32;

    if (geom_ok && PPB >= 2) {
        int chunk = ((E + NBLK - 1) / NBLK + 3) & ~3;
        int PB = (BN + 255) / 256;
        prep_kernel<<<PB + NBLK, 256, 0, stream>>>(rel, basis, bch, pos4, ghist,
                                                   BN, N, E, chunk, PB);
        scan_kernel<<<1, 1024, 0, stream>>>(ghist);
        scatter_kernel<<<NBLK, 256, 0, stream>>>(shifts, src, dst, bch, ghist,
                                                 recs, E, chunk);
        accum_kernel<<<B * PPB, 256, 0, stream>>>(recs, pos4, ghist, partials,
                                                  E, N, PPB);
        final_kernel<<<(BN + 255) / 256, 256, 0, stream>>>(partials, basis, raw,
                                                           (float*)d_out, BN, N, PPB);
    } else {
        // fallback: device-scope atomics
        float* pos  = (float*)d_ws;
        float* cart = pos + (size_t)BN * 3;
        float* rcp  = cart + (size_t)BN * 3;
        hipMemsetAsync(cart, 0, (size_t)BN * 3 * sizeof(float), stream);
        pos3_kernel<<<(BN + 255) / 256, 256, 0, stream>>>(rel, basis, pos, BN, N);
        inv_kernel<<<1, 64, 0, stream>>>(basis, rcp, B);
        edge_kernel_dev<<<(E + 255) / 256, 256, 0, stream>>>(pos, shifts, src, dst, bch,
                                                             cart, E, N);
        out_kernel<<<(BN + 255) / 256, 256, 0, stream>>>(cart, rcp, raw,
                                                         (float*)d_out, BN, N);
    }
}

// Round 11
// 82.772 us; speedup vs baseline: 1.2231x; 1.0017x over previous
//
#include <hip/hip_runtime.h>

// ---- fast-path geometry ----
#define NBLK 2048              // hist/scatter blocks
#define NBUK 16                // max batches (bucket = batch)
#define MAXN 4096              // max nodes/batch (48 KB acc + 64 KB pos LDS)
#define SCAN_N (NBUK * NBLK)   // 32768 ghist entries
#define MAXPPB 16              // accum partials per batch (grid = B*PPB = 256 blocks)

// K1: blocks [0,PB): pos4[idx] = rel@basis (padded float4); blocks [PB,PB+NBLK): batch histogram
__global__ void prep_kernel(const float* __restrict__ rel,
                            const float* __restrict__ basis,
                            const int* __restrict__ bch,
                            float4* __restrict__ pos4,
                            int* __restrict__ ghist,
                            int BN, int N, int E, int chunk, int PB) {
    int blk = blockIdx.x, tid = threadIdx.x;
    if (blk < PB) {
        int idx = blk * 256 + tid;
        if (idx < BN) {
            int b = idx / N;
            const float* bm = basis + b * 9;
            float x = rel[idx * 3 + 0], y = rel[idx * 3 + 1], z = rel[idx * 3 + 2];
            float4 p;
            p.x = x * bm[0] + y * bm[3] + z * bm[6];
            p.y = x * bm[1] + y * bm[4] + z * bm[7];
            p.z = x * bm[2] + y * bm[5] + z * bm[8];
            p.w = 0.0f;
            pos4[idx] = p;
        }
        return;
    }
    __shared__ int h[NBUK];
    int hb = blk - PB;
    if (tid < NBUK) h[tid] = 0;
    __syncthreads();
    int lo = hb * chunk, hi = min(E, lo + chunk);
    for (int e0 = lo + tid * 4; e0 < hi; e0 += 1024) {
        if (e0 + 3 < hi) {
            int4 b4 = *(const int4*)(bch + e0);
            atomicAdd(&h[b4.x], 1);
            atomicAdd(&h[b4.y], 1);
            atomicAdd(&h[b4.z], 1);
            atomicAdd(&h[b4.w], 1);
        } else {
            for (int e = e0; e < hi; ++e) atomicAdd(&h[bch[e]], 1);
        }
    }
    __syncthreads();
    if (tid < NBUK) ghist[tid * NBLK + hb] = h[tid];
}

// K2: exclusive scan of all SCAN_N entries, single block of 1024 (32 entries/thread)
__global__ void scan_kernel(int* __restrict__ g) {
    __shared__ int tp[1024];
    int tid = threadIdx.x;
    int base = tid * 32;
    int v[32];
    int s = 0;
#pragma unroll
    for (int i = 0; i < 8; ++i) {
        int4 q = *(const int4*)(g + base + i * 4);
        v[i * 4 + 0] = q.x; v[i * 4 + 1] = q.y;
        v[i * 4 + 2] = q.z; v[i * 4 + 3] = q.w;
        s += q.x + q.y + q.z + q.w;
    }
    tp[tid] = s;
    for (int off = 1; off < 1024; off <<= 1) {
        __syncthreads();
        int t = (tid >= off) ? tp[tid - off] : 0;
        __syncthreads();
        tp[tid] += t;
    }
    __syncthreads();
    int run = tp[tid] - s;  // exclusive base
#pragma unroll
    for (int i = 0; i < 8; ++i) {
        int4 q;
        q.x = run; run += v[i * 4 + 0];
        q.y = run; run += v[i * 4 + 1];
        q.z = run; run += v[i * 4 + 2];
        q.w = run; run += v[i * 4 + 3];
        *(int4*)(g + base + i * 4) = q;
    }
}

// K3: pure reorder — record = (shift.xyz, src|dst<<12) grouped by batch. No gathers, no math.
__global__ void scatter_kernel(const float* __restrict__ shifts,
                               const int* __restrict__ src,
                               const int* __restrict__ dst,
                               const int* __restrict__ bch,
                               const int* __restrict__ ghist,
                               float4* __restrict__ recs,
                               int E, int chunk) {
    __shared__ int cur[NBUK];
    int tid = threadIdx.x, blk = blockIdx.x;
    if (tid < NBUK) cur[tid] = ghist[tid * NBLK + blk];
    __syncthreads();
    int lo = blk * chunk, hi = min(E, lo + chunk);
    for (int e0 = lo + tid * 4; e0 < hi; e0 += 1024) {
        if (e0 + 3 < hi) {
            int4 s4 = *(const int4*)(src + e0);
            int4 d4 = *(const int4*)(dst + e0);
            int4 b4 = *(const int4*)(bch + e0);
            const float4* sh4 = (const float4*)(shifts + (size_t)e0 * 3);
            float4 A = sh4[0], Bv = sh4[1], C = sh4[2];
            int se[4] = {s4.x, s4.y, s4.z, s4.w};
            int de[4] = {d4.x, d4.y, d4.z, d4.w};
            int be[4] = {b4.x, b4.y, b4.z, b4.w};
            float sx[4] = {A.x, A.w, Bv.z, C.y};
            float sy[4] = {A.y, Bv.x, Bv.w, C.z};
            float sz[4] = {A.z, Bv.y, C.x, C.w};
#pragma unroll
            for (int k = 0; k < 4; ++k) {
                int slot = atomicAdd(&cur[be[k]], 1);
                float4 rec;
                rec.x = sx[k]; rec.y = sy[k]; rec.z = sz[k];
                rec.w = __int_as_float(se[k] | (de[k] << 12));
                recs[slot] = rec;
            }
        } else {
            for (int e = e0; e < hi; ++e) {
                int slot = atomicAdd(&cur[bch[e]], 1);
                float4 rec;
                rec.x = shifts[(size_t)e * 3 + 0];
                rec.y = shifts[(size_t)e * 3 + 1];
                rec.z = shifts[(size_t)e * 3 + 2];
                rec.w = __int_as_float(src[e] | (dst[e] << 12));
                recs[slot] = rec;
            }
        }
    }
}

// K4: per (batch, slice): pos slice staged in LDS (64 KB) + 48 KB LDS accumulator.
// 1 vmem/record (coalesced rec stream, 4-way batched); gathers are ds_read_b128.
__global__ __launch_bounds__(256, 1)
void accum_kernel(const float4* __restrict__ recs,
                  const float4* __restrict__ pos4,
                  const int* __restrict__ ghist,
                  float* __restrict__ partials,
                  int E, int N, int PPB) {
    __shared__ float4 pos_s[MAXN];   // 64 KB
    __shared__ float acc[MAXN * 3];  // 48 KB
    int bx = blockIdx.x;
    int b = bx / PPB, p = bx % PPB;
    int tid = threadIdx.x;
    int n3 = N * 3;
    for (int i = tid * 4; i < n3; i += 1024)
        *(float4*)&acc[i] = make_float4(0.f, 0.f, 0.f, 0.f);
    const float4* pb = pos4 + (size_t)b * N;
    for (int j = tid; j < N; j += 256) pos_s[j] = pb[j];
    __syncthreads();
    int i0 = ghist[b * NBLK];
    int i1 = (b + 1 < NBUK) ? ghist[(b + 1) * NBLK] : E;
    long long len = (long long)(i1 - i0);
    int lo = i0 + (int)(len * p / PPB);
    int hi = i0 + (int)(len * (p + 1) / PPB);

#define PROC(r)                                                        \
    {                                                                  \
        int u = __float_as_int((r).w);                                 \
        int s_ = u & 4095, d_ = (u >> 12) & 4095;                      \
        float4 P = pos_s[d_], Q = pos_s[s_];                           \
        float dx = P.x - Q.x + (r).x;                                  \
        float dy = P.y - Q.y + (r).y;                                  \
        float dz = P.z - Q.z + (r).z;                                  \
        float rr = sqrtf(dx * dx + dy * dy + dz * dz);                 \
        float pref = 2.0f * (rr - 3.0f) / (rr + 1e-8f);                \
        atomicAdd(&acc[s_ * 3 + 0], pref * dx);                        \
        atomicAdd(&acc[s_ * 3 + 1], pref * dy);                        \
        atomicAdd(&acc[s_ * 3 + 2], pref * dz);                        \
    }

    int i = lo + tid;
    for (; i + 768 < hi; i += 1024) {
        float4 r0 = recs[i];
        float4 r1 = recs[i + 256];
        float4 r2 = recs[i + 512];
        float4 r3 = recs[i + 768];
        PROC(r0); PROC(r1); PROC(r2); PROC(r3);
    }
    for (; i < hi; i += 256) {
        float4 r = recs[i];
        PROC(r);
    }
#undef PROC
    __syncthreads();
    float* dstp = partials + (size_t)bx * n3;
    for (int i2 = tid * 4; i2 < n3; i2 += 1024)
        *(float4*)&dstp[i2] = *(const float4*)&acc[i2];
}

// K5: sum PPB partials (coalesced), fold 3x3 inverse, transform + residual
__global__ void final_kernel(const float* __restrict__ partials,
                             const float* __restrict__ basis,
                             const float* __restrict__ raw,
                             float* __restrict__ out,
                             int BN, int N, int PPB) {
    int idx = blockIdx.x * blockDim.x + threadIdx.x;
    if (idx >= BN) return;
    int b = idx / N;
    int nl = idx - b * N;
    int n3 = N * 3;
    const float* pp = partials + (size_t)b * PPB * n3 + (size_t)nl * 3;
    float x = 0.f, y = 0.f, z = 0.f;
    for (int p = 0; p < PPB; ++p) {
        x += pp[0]; y += pp[1]; z += pp[2];
        pp += n3;
    }
    const float* m = basis + b * 9;
    float a00 = m[0], a01 = m[1], a02 = m[2];
    float a10 = m[3], a11 = m[4], a12 = m[5];
    float a20 = m[6], a21 = m[7], a22 = m[8];
    float c00 = a11 * a22 - a12 * a21;
    float c01 = -(a10 * a22 - a12 * a20);
    float c02 = a10 * a21 - a11 * a20;
    float det = a00 * c00 + a01 * c01 + a02 * c02;
    float id = 1.0f / det;
    float rm0 = c00 * id;
    float rm1 = (a02 * a21 - a01 * a22) * id;
    float rm2 = (a01 * a12 - a02 * a11) * id;
    float rm3 = c01 * id;
    float rm4 = (a00 * a22 - a02 * a20) * id;
    float rm5 = (a02 * a10 - a00 * a12) * id;
    float rm6 = c02 * id;
    float rm7 = (a01 * a20 - a00 * a21) * id;
    float rm8 = (a00 * a11 - a01 * a10) * id;
    out[idx * 3 + 0] = raw[idx * 3 + 0] + x * rm0 + y * rm3 + z * rm6;
    out[idx * 3 + 1] = raw[idx * 3 + 1] + x * rm1 + y * rm4 + z * rm7;
    out[idx * 3 + 2] = raw[idx * 3 + 2] + x * rm2 + y * rm5 + z * rm8;
}

// ---------------- fallback (device atomics, known-good ~315 us) ----------------
__global__ void pos3_kernel(const float* __restrict__ rel,
                            const float* __restrict__ basis,
                            float* __restrict__ pos,
                            int BN, int N) {
    int idx = blockIdx.x * blockDim.x + threadIdx.x;
    if (idx >= BN) return;
    int b = idx / N;
    const float* bm = basis + b * 9;
    float x = rel[idx * 3 + 0], y = rel[idx * 3 + 1], z = rel[idx * 3 + 2];
    pos[idx * 3 + 0] = x * bm[0] + y * bm[3] + z * bm[6];
    pos[idx * 3 + 1] = x * bm[1] + y * bm[4] + z * bm[7];
    pos[idx * 3 + 2] = x * bm[2] + y * bm[5] + z * bm[8];
}

__global__ void inv_kernel(const float* __restrict__ basis,
                           float* __restrict__ recip, int B) {
    int b = blockIdx.x * blockDim.x + threadIdx.x;
    if (b >= B) return;
    const float* m = basis + b * 9;
    float a00 = m[0], a01 = m[1], a02 = m[2];
    float a10 = m[3], a11 = m[4], a12 = m[5];
    float a20 = m[6], a21 = m[7], a22 = m[8];
    float c00 = a11 * a22 - a12 * a21;
    float c01 = -(a10 * a22 - a12 * a20);
    float c02 = a10 * a21 - a11 * a20;
    float det = a00 * c00 + a01 * c01 + a02 * c02;
    float id = 1.0f / det;
    float* r = recip + b * 9;
    r[0] = c00 * id;
    r[1] = (a02 * a21 - a01 * a22) * id;
    r[2] = (a01 * a12 - a02 * a11) * id;
    r[3] = c01 * id;
    r[4] = (a00 * a22 - a02 * a20) * id;
    r[5] = (a02 * a10 - a00 * a12) * id;
    r[6] = c02 * id;
    r[7] = (a01 * a20 - a00 * a21) * id;
    r[8] = (a00 * a11 - a01 * a10) * id;
}

__global__ void edge_kernel_dev(const float* __restrict__ pos,
                                const float* __restrict__ shifts,
                                const int* __restrict__ src,
                                const int* __restrict__ dst,
                                const int* __restrict__ bch,
                                float* __restrict__ cart,
                                int E, int N) {
    int e = blockIdx.x * blockDim.x + threadIdx.x;
    if (e >= E) return;
    int b = bch[e], s = src[e], d = dst[e];
    int base = b * N;
    const float* pd = pos + (size_t)(base + d) * 3;
    const float* ps = pos + (size_t)(base + s) * 3;
    float dx = pd[0] - ps[0] + shifts[(size_t)e * 3 + 0];
    float dy = pd[1] - ps[1] + shifts[(size_t)e * 3 + 1];
    float dz = pd[2] - ps[2] + shifts[(size_t)e * 3 + 2];
    float r = sqrtf(dx * dx + dy * dy + dz * dz);
    float pref = 2.0f * (r - 3.0f) / (r + 1e-8f);
    float* c = cart + (size_t)(base + s) * 3;
    atomicAdd(&c[0], pref * dx);
    atomicAdd(&c[1], pref * dy);
    atomicAdd(&c[2], pref * dz);
}

__global__ void out_kernel(const float* __restrict__ cart,
                           const float* __restrict__ recip,
                           const float* __restrict__ raw,
                           float* __restrict__ out,
                           int BN, int N) {
    int idx = blockIdx.x * blockDim.x + threadIdx.x;
    if (idx >= BN) return;
    int b = idx / N;
    const float* rm = recip + b * 9;
    float x = cart[idx * 3 + 0], y = cart[idx * 3 + 1], z = cart[idx * 3 + 2];
    out[idx * 3 + 0] = raw[idx * 3 + 0] + x * rm[0] + y * rm[3] + z * rm[6];
    out[idx * 3 + 1] = raw[idx * 3 + 1] + x * rm[1] + y * rm[4] + z * rm[7];
    out[idx * 3 + 2] = raw[idx * 3 + 2] + x * rm[2] + y * rm[5] + z * rm[8];
}

extern "C" void kernel_launch(void* const* d_in, const int* in_sizes, int n_in,
                              void* d_out, int out_size, void* d_ws, size_t ws_size,
                              hipStream_t stream) {
    const float* rel    = (const float*)d_in[0];
    const float* basis  = (const float*)d_in[1];
    const float* shifts = (const float*)d_in[2];
    const float* raw    = (const float*)d_in[3];
    const int*   src    = (const int*)d_in[4];
    const int*   dst    = (const int*)d_in[5];
    const int*   bch    = (const int*)d_in[6];

    int B  = in_sizes[1] / 9;
    int BN = in_sizes[0] / 3;
    int N  = BN / B;
    int E  = in_sizes[4];

    // ws layout: recs[E] f4 | pos4[BN] f4 | ghist[SCAN_N] i32 | partials[B*PPB*N*3] f32
    char* w = (char*)d_ws;
    float4* recs  = (float4*)w;  w += (size_t)E * 16;
    float4* pos4  = (float4*)w;  w += (size_t)BN * 16;
    int*    ghist = (int*)w;     w += (size_t)SCAN_N * 4;
    float*  partials = (float*)w;
    size_t base_bytes = (size_t)(w - (char*)d_ws);

    bool geom_ok = (B >= 1) && (B <= NBUK) && (N >= 4) && (N <= MAXN) &&
                   (N % 4 == 0) && (BN == B * N) && (E >= 4);
    size_t per_ppb = (size_t)B * N * 3 * 4;
    int PPB = 0;
    if (geom_ok && ws_size > base_bytes)
        PPB = (int)((ws_size - base_bytes) / per_ppb);
    if (PPB > MAXPPB) PPB = MAXPPB;

    if (geom_ok && PPB >= 2) {
        int chunk = ((E + NBLK - 1) / NBLK + 3) & ~3;
        int PB = (BN + 255) / 256;
        prep_kernel<<<PB + NBLK, 256, 0, stream>>>(rel, basis, bch, pos4, ghist,
                                                   BN, N, E, chunk, PB);
        scan_kernel<<<1, 1024, 0, stream>>>(ghist);
        scatter_kernel<<<NBLK, 256, 0, stream>>>(shifts, src, dst, bch, ghist,
                                                 recs, E, chunk);
        accum_kernel<<<B * PPB, 256, 0, stream>>>(recs, pos4, ghist, partials,
                                                  E, N, PPB);
        final_kernel<<<(BN + 255) / 256, 256, 0, stream>>>(partials, basis, raw,
                                                           (float*)d_out, BN, N, PPB);
    } else {
        // fallback: device-scope atomics
        float* pos  = (float*)d_ws;
        float* cart = pos + (size_t)BN * 3;
        float* rcp  = cart + (size_t)BN * 3;
        hipMemsetAsync(cart, 0, (size_t)BN * 3 * sizeof(float), stream);
        pos3_kernel<<<(BN + 255) / 256, 256, 0, stream>>>(rel, basis, pos, BN, N);
        inv_kernel<<<1, 64, 0, stream>>>(basis, rcp, B);
        edge_kernel_dev<<<(E + 255) / 256, 256, 0, stream>>>(pos, shifts, src, dst, bch,
                                                             cart, E, N);
        out_kernel<<<(BN + 255) / 256, 256, 0, stream>>>(cart, rcp, raw,
                                                         (float*)d_out, BN, N);
    }
}

// Round 12
// 77.848 us; speedup vs baseline: 1.3005x; 1.0633x over previous
//
#include <hip/hip_runtime.h>

// ---- fast-path geometry ----
#define NBLK 2048               // hist/scatter blocks
#define NBUK 16                 // max batches
#define NQ   4                  // node-quarters per batch
#define QSH  10                 // 1024 nodes per quarter
#define NBUCK (NBUK * NQ)       // 64 buckets
#define MAXN 4096               // max nodes/batch (NQ << QSH)
#define SCAN_N (NBUCK * NBLK)   // 131072 ghist entries
#define SCAN_BS 1024
#define MAXPPB 32               // accum slices per bucket

// K1: blocks [0,PB): pos4[idx] = rel@basis; blocks [PB,PB+NBLK): (batch,quarter) histogram
__global__ void prep_kernel(const float* __restrict__ rel,
                            const float* __restrict__ basis,
                            const int* __restrict__ src,
                            const int* __restrict__ bch,
                            float4* __restrict__ pos4,
                            int* __restrict__ ghist,
                            int BN, int N, int E, int chunk, int PB) {
    int blk = blockIdx.x, tid = threadIdx.x;
    if (blk < PB) {
        int idx = blk * 256 + tid;
        if (idx < BN) {
            int b = idx / N;
            const float* bm = basis + b * 9;
            float x = rel[idx * 3 + 0], y = rel[idx * 3 + 1], z = rel[idx * 3 + 2];
            float4 p;
            p.x = x * bm[0] + y * bm[3] + z * bm[6];
            p.y = x * bm[1] + y * bm[4] + z * bm[7];
            p.z = x * bm[2] + y * bm[5] + z * bm[8];
            p.w = 0.0f;
            pos4[idx] = p;
        }
        return;
    }
    __shared__ int h[NBUCK];
    int hb = blk - PB;
    if (tid < NBUCK) h[tid] = 0;
    __syncthreads();
    int lo = hb * chunk, hi = min(E, lo + chunk);
    for (int e0 = lo + tid * 4; e0 < hi; e0 += 1024) {
        if (e0 + 3 < hi) {
            int4 b4 = *(const int4*)(bch + e0);
            int4 s4 = *(const int4*)(src + e0);
            atomicAdd(&h[b4.x * NQ + (s4.x >> QSH)], 1);
            atomicAdd(&h[b4.y * NQ + (s4.y >> QSH)], 1);
            atomicAdd(&h[b4.z * NQ + (s4.z >> QSH)], 1);
            atomicAdd(&h[b4.w * NQ + (s4.w >> QSH)], 1);
        } else {
            for (int e = e0; e < hi; ++e)
                atomicAdd(&h[bch[e] * NQ + (src[e] >> QSH)], 1);
        }
    }
    __syncthreads();
    if (tid < NBUCK) ghist[tid * NBLK + hb] = h[tid];
}

// K2a: scan 1024-element tiles (exclusive, in place), emit tile sums (128 tiles)
__global__ void scan1_kernel(int* __restrict__ g, int* __restrict__ bsums) {
    __shared__ int tp[256];
    int tid = threadIdx.x;
    int base = blockIdx.x * SCAN_BS + tid * 4;
    int v0 = g[base], v1 = g[base + 1], v2 = g[base + 2], v3 = g[base + 3];
    int s = v0 + v1 + v2 + v3;
    tp[tid] = s;
    for (int off = 1; off < 256; off <<= 1) {
        __syncthreads();
        int t = (tid >= off) ? tp[tid - off] : 0;
        __syncthreads();
        tp[tid] += t;
    }
    __syncthreads();
    int incl = tp[tid];
    int excl = incl - s;
    g[base]     = excl;
    g[base + 1] = excl + v0;
    g[base + 2] = excl + v0 + v1;
    g[base + 3] = excl + v0 + v1 + v2;
    if (tid == 255) bsums[blockIdx.x] = incl;
}

// K2b: exclusive scan of tile sums (n <= 1024), one block
__global__ void scan2_kernel(int* __restrict__ bsums, int n) {
    __shared__ int tp[1024];
    int tid = threadIdx.x;
    int v = (tid < n) ? bsums[tid] : 0;
    tp[tid] = v;
    for (int off = 1; off < 1024; off <<= 1) {
        __syncthreads();
        int t = (tid >= off) ? tp[tid - off] : 0;
        __syncthreads();
        tp[tid] += t;
    }
    __syncthreads();
    if (tid < n) bsums[tid] = tp[tid] - v;
}

// K3: pure reorder — record = (shift.xyz, src|dst<<12) grouped by (batch,quarter) bucket
__global__ void scatter_kernel(const float* __restrict__ shifts,
                               const int* __restrict__ src,
                               const int* __restrict__ dst,
                               const int* __restrict__ bch,
                               const int* __restrict__ ghist,
                               const int* __restrict__ bsums,
                               float4* __restrict__ recs,
                               int E, int chunk) {
    __shared__ int cur[NBUCK];
    int tid = threadIdx.x, blk = blockIdx.x;
    if (tid < NBUCK) {
        int idx = tid * NBLK + blk;
        cur[tid] = ghist[idx] + bsums[idx >> 10];
    }
    __syncthreads();
    int lo = blk * chunk, hi = min(E, lo + chunk);
    for (int e0 = lo + tid * 4; e0 < hi; e0 += 1024) {
        if (e0 + 3 < hi) {
            int4 s4 = *(const int4*)(src + e0);
            int4 d4 = *(const int4*)(dst + e0);
            int4 b4 = *(const int4*)(bch + e0);
            const float4* sh4 = (const float4*)(shifts + (size_t)e0 * 3);
            float4 A = sh4[0], Bv = sh4[1], C = sh4[2];
            int se[4] = {s4.x, s4.y, s4.z, s4.w};
            int de[4] = {d4.x, d4.y, d4.z, d4.w};
            int be[4] = {b4.x, b4.y, b4.z, b4.w};
            float sx[4] = {A.x, A.w, Bv.z, C.y};
            float sy[4] = {A.y, Bv.x, Bv.w, C.z};
            float sz[4] = {A.z, Bv.y, C.x, C.w};
#pragma unroll
            for (int k = 0; k < 4; ++k) {
                int slot = atomicAdd(&cur[be[k] * NQ + (se[k] >> QSH)], 1);
                float4 rec;
                rec.x = sx[k]; rec.y = sy[k]; rec.z = sz[k];
                rec.w = __int_as_float(se[k] | (de[k] << 12));
                recs[slot] = rec;
            }
        } else {
            for (int e = e0; e < hi; ++e) {
                int slot = atomicAdd(&cur[bch[e] * NQ + (src[e] >> QSH)], 1);
                float4 rec;
                rec.x = shifts[(size_t)e * 3 + 0];
                rec.y = shifts[(size_t)e * 3 + 1];
                rec.z = shifts[(size_t)e * 3 + 2];
                rec.w = __int_as_float(src[e] | (dst[e] << 12));
                recs[slot] = rec;
            }
        }
    }
}

// K4: per (bucket, slice): 12 KB LDS accumulator (1024 nodes), global pos gathers (L2-hot).
__global__ __launch_bounds__(256, 4)
void accum_kernel(const float4* __restrict__ recs,
                  const float4* __restrict__ pos4,
                  const int* __restrict__ ghist,
                  const int* __restrict__ bsums,
                  float* __restrict__ partials,
                  int E, int N, int PPB) {
    __shared__ float acc[(1 << QSH) * 3];  // 12 KB
    int bx = blockIdx.x;
    int bucket = bx / PPB, p = bx - bucket * PPB;
    int b = bucket >> 2, q = bucket & 3;   // NQ == 4
    int nb = q << QSH;
    int tid = threadIdx.x;
    for (int i = tid * 4; i < (1 << QSH) * 3; i += 1024)
        *(float4*)&acc[i] = make_float4(0.f, 0.f, 0.f, 0.f);
    __syncthreads();
    int g0 = bucket * NBLK;
    int i0 = ghist[g0] + bsums[g0 >> 10];
    int i1 = E;
    if (bucket + 1 < NBUCK) {
        int g1 = (bucket + 1) * NBLK;
        i1 = ghist[g1] + bsums[g1 >> 10];
    }
    const float4* pb = pos4 + (size_t)b * N;
    long long len = (long long)(i1 - i0);
    int lo = i0 + (int)(len * p / PPB);
    int hi = i0 + (int)(len * (p + 1) / PPB);

#define PROC(r)                                                        \
    {                                                                  \
        int u = __float_as_int((r).w);                                 \
        int s_ = u & 4095, d_ = (u >> 12) & 4095;                      \
        float4 P = pb[d_], Q = pb[s_];                                 \
        float dx = P.x - Q.x + (r).x;                                  \
        float dy = P.y - Q.y + (r).y;                                  \
        float dz = P.z - Q.z + (r).z;                                  \
        float rr = sqrtf(dx * dx + dy * dy + dz * dz);                 \
        float pref = 2.0f * (rr - 3.0f) / (rr + 1e-8f);                \
        int nl = s_ - nb;                                              \
        atomicAdd(&acc[nl * 3 + 0], pref * dx);                        \
        atomicAdd(&acc[nl * 3 + 1], pref * dy);                        \
        atomicAdd(&acc[nl * 3 + 2], pref * dz);                        \
    }

    int i = lo + tid;
    for (; i + 768 < hi; i += 1024) {
        float4 r0 = recs[i];
        float4 r1 = recs[i + 256];
        float4 r2 = recs[i + 512];
        float4 r3 = recs[i + 768];
        PROC(r0); PROC(r1); PROC(r2); PROC(r3);
    }
    for (; i < hi; i += 256) {
        float4 r = recs[i];
        PROC(r);
    }
#undef PROC
    __syncthreads();
    float* dstp = partials + (size_t)bx * ((1 << QSH) * 3);
    for (int i2 = tid * 4; i2 < (1 << QSH) * 3; i2 += 1024)
        *(float4*)&dstp[i2] = *(const float4*)&acc[i2];
}

// K5: sum PPB partials per node, fold 3x3 inverse, transform + residual
__global__ void final_kernel(const float* __restrict__ partials,
                             const float* __restrict__ basis,
                             const float* __restrict__ raw,
                             float* __restrict__ out,
                             int BN, int N, int PPB) {
    int idx = blockIdx.x * blockDim.x + threadIdx.x;
    if (idx >= BN) return;
    int b = idx / N;
    int n = idx - b * N;
    int q = n >> QSH;
    int nl = n - (q << QSH);
    int bucket = b * NQ + q;
    const int Q3 = (1 << QSH) * 3;
    const float* pp = partials + (size_t)bucket * PPB * Q3 + (size_t)nl * 3;
    float x = 0.f, y = 0.f, z = 0.f;
    for (int p = 0; p < PPB; ++p) {
        x += pp[0]; y += pp[1]; z += pp[2];
        pp += Q3;
    }
    const float* m = basis + b * 9;
    float a00 = m[0], a01 = m[1], a02 = m[2];
    float a10 = m[3], a11 = m[4], a12 = m[5];
    float a20 = m[6], a21 = m[7], a22 = m[8];
    float c00 = a11 * a22 - a12 * a21;
    float c01 = -(a10 * a22 - a12 * a20);
    float c02 = a10 * a21 - a11 * a20;
    float det = a00 * c00 + a01 * c01 + a02 * c02;
    float id = 1.0f / det;
    float rm0 = c00 * id;
    float rm1 = (a02 * a21 - a01 * a22) * id;
    float rm2 = (a01 * a12 - a02 * a11) * id;
    float rm3 = c01 * id;
    float rm4 = (a00 * a22 - a02 * a20) * id;
    float rm5 = (a02 * a10 - a00 * a12) * id;
    float rm6 = c02 * id;
    float rm7 = (a01 * a20 - a00 * a21) * id;
    float rm8 = (a00 * a11 - a01 * a10) * id;
    out[idx * 3 + 0] = raw[idx * 3 + 0] + x * rm0 + y * rm3 + z * rm6;
    out[idx * 3 + 1] = raw[idx * 3 + 1] + x * rm1 + y * rm4 + z * rm7;
    out[idx * 3 + 2] = raw[idx * 3 + 2] + x * rm2 + y * rm5 + z * rm8;
}

// ---------------- fallback (device atomics, known-good ~315 us) ----------------
__global__ void pos3_kernel(const float* __restrict__ rel,
                            const float* __restrict__ basis,
                            float* __restrict__ pos,
                            int BN, int N) {
    int idx = blockIdx.x * blockDim.x + threadIdx.x;
    if (idx >= BN) return;
    int b = idx / N;
    const float* bm = basis + b * 9;
    float x = rel[idx * 3 + 0], y = rel[idx * 3 + 1], z = rel[idx * 3 + 2];
    pos[idx * 3 + 0] = x * bm[0] + y * bm[3] + z * bm[6];
    pos[idx * 3 + 1] = x * bm[1] + y * bm[4] + z * bm[7];
    pos[idx * 3 + 2] = x * bm[2] + y * bm[5] + z * bm[8];
}

__global__ void inv_kernel(const float* __restrict__ basis,
                           float* __restrict__ recip, int B) {
    int b = blockIdx.x * blockDim.x + threadIdx.x;
    if (b >= B) return;
    const float* m = basis + b * 9;
    float a00 = m[0], a01 = m[1], a02 = m[2];
    float a10 = m[3], a11 = m[4], a12 = m[5];
    float a20 = m[6], a21 = m[7], a22 = m[8];
    float c00 = a11 * a22 - a12 * a21;
    float c01 = -(a10 * a22 - a12 * a20);
    float c02 = a10 * a21 - a11 * a20;
    float det = a00 * c00 + a01 * c01 + a02 * c02;
    float id = 1.0f / det;
    float* r = recip + b * 9;
    r[0] = c00 * id;
    r[1] = (a02 * a21 - a01 * a22) * id;
    r[2] = (a01 * a12 - a02 * a11) * id;
    r[3] = c01 * id;
    r[4] = (a00 * a22 - a02 * a20) * id;
    r[5] = (a02 * a10 - a00 * a12) * id;
    r[6] = c02 * id;
    r[7] = (a01 * a20 - a00 * a21) * id;
    r[8] = (a00 * a11 - a01 * a10) * id;
}

__global__ void edge_kernel_dev(const float* __restrict__ pos,
                                const float* __restrict__ shifts,
                                const int* __restrict__ src,
                                const int* __restrict__ dst,
                                const int* __restrict__ bch,
                                float* __restrict__ cart,
                                int E, int N) {
    int e = blockIdx.x * blockDim.x + threadIdx.x;
    if (e >= E) return;
    int b = bch[e], s = src[e], d = dst[e];
    int base = b * N;
    const float* pd = pos + (size_t)(base + d) * 3;
    const float* ps = pos + (size_t)(base + s) * 3;
    float dx = pd[0] - ps[0] + shifts[(size_t)e * 3 + 0];
    float dy = pd[1] - ps[1] + shifts[(size_t)e * 3 + 1];
    float dz = pd[2] - ps[2] + shifts[(size_t)e * 3 + 2];
    float r = sqrtf(dx * dx + dy * dy + dz * dz);
    float pref = 2.0f * (r - 3.0f) / (r + 1e-8f);
    float* c = cart + (size_t)(base + s) * 3;
    atomicAdd(&c[0], pref * dx);
    atomicAdd(&c[1], pref * dy);
    atomicAdd(&c[2], pref * dz);
}

__global__ void out_kernel(const float* __restrict__ cart,
                           const float* __restrict__ recip,
                           const float* __restrict__ raw,
                           float* __restrict__ out,
                           int BN, int N) {
    int idx = blockIdx.x * blockDim.x + threadIdx.x;
    if (idx >= BN) return;
    int b = idx / N;
    const float* rm = recip + b * 9;
    float x = cart[idx * 3 + 0], y = cart[idx * 3 + 1], z = cart[idx * 3 + 2];
    out[idx * 3 + 0] = raw[idx * 3 + 0] + x * rm[0] + y * rm[3] + z * rm[6];
    out[idx * 3 + 1] = raw[idx * 3 + 1] + x * rm[1] + y * rm[4] + z * rm[7];
    out[idx * 3 + 2] = raw[idx * 3 + 2] + x * rm[2] + y * rm[5] + z * rm[8];
}

extern "C" void kernel_launch(void* const* d_in, const int* in_sizes, int n_in,
                              void* d_out, int out_size, void* d_ws, size_t ws_size,
                              hipStream_t stream) {
    const float* rel    = (const float*)d_in[0];
    const float* basis  = (const float*)d_in[1];
    const float* shifts = (const float*)d_in[2];
    const float* raw    = (const float*)d_in[3];
    const int*   src    = (const int*)d_in[4];
    const int*   dst    = (const int*)d_in[5];
    const int*   bch    = (const int*)d_in[6];

    int B  = in_sizes[1] / 9;
    int BN = in_sizes[0] / 3;
    int N  = BN / B;
    int E  = in_sizes[4];

    // ws layout: recs[E] f4 | pos4[BN] f4 | ghist[SCAN_N] i32 | bsums[256] i32 | partials
    char* w = (char*)d_ws;
    float4* recs  = (float4*)w;  w += (size_t)E * 16;
    float4* pos4  = (float4*)w;  w += (size_t)BN * 16;
    int*    ghist = (int*)w;     w += (size_t)SCAN_N * 4;
    int*    bsums = (int*)w;     w += 256 * 4;
    float*  partials = (float*)w;
    size_t base_bytes = (size_t)(w - (char*)d_ws);

    bool geom_ok = (B >= 1) && (B <= NBUK) && (N >= 4) && (N <= MAXN) &&
                   (BN == B * N) && (E >= 4);
    size_t per_ppb = (size_t)B * NQ * (1 << QSH) * 3 * 4;  // one slice across all buckets
    int PPB = 0;
    if (geom_ok && ws_size > base_bytes)
        PPB = (int)((ws_size - base_bytes) / per_ppb);
    if (PPB > MAXPPB) PPB = MAXPPB;

    if (geom_ok && PPB >= 2) {
        int chunk = ((E + NBLK - 1) / NBLK + 3) & ~3;
        int PB = (BN + 255) / 256;
        prep_kernel<<<PB + NBLK, 256, 0, stream>>>(rel, basis, src, bch, pos4, ghist,
                                                   BN, N, E, chunk, PB);
        scan1_kernel<<<SCAN_N / SCAN_BS, 256, 0, stream>>>(ghist, bsums);
        scan2_kernel<<<1, 1024, 0, stream>>>(bsums, SCAN_N / SCAN_BS);
        scatter_kernel<<<NBLK, 256, 0, stream>>>(shifts, src, dst, bch, ghist, bsums,
                                                 recs, E, chunk);
        accum_kernel<<<B * NQ * PPB, 256, 0, stream>>>(recs, pos4, ghist, bsums,
                                                       partials, E, N, PPB);
        final_kernel<<<(BN + 255) / 256, 256, 0, stream>>>(partials, basis, raw,
                                                           (float*)d_out, BN, N, PPB);
    } else {
        // fallback: device-scope atomics
        float* pos  = (float*)d_ws;
        float* cart = pos + (size_t)BN * 3;
        float* rcp  = cart + (size_t)BN * 3;
        hipMemsetAsync(cart, 0, (size_t)BN * 3 * sizeof(float), stream);
        pos3_kernel<<<(BN + 255) / 256, 256, 0, stream>>>(rel, basis, pos, BN, N);
        inv_kernel<<<1, 64, 0, stream>>>(basis, rcp, B);
        edge_kernel_dev<<<(E + 255) / 256, 256, 0, stream>>>(pos, shifts, src, dst, bch,
                                                             cart, E, N);
        out_kernel<<<(BN + 255) / 256, 256, 0, stream>>>(cart, rcp, raw,
                                                         (float*)d_out, BN, N);
    }
}